// Round 24
// baseline (966.960 us; speedup 1.0000x reference)
//
#include <hip/hip_runtime.h>

// Persistent cooperative LSTM decoder. NLAYERS=4, NHID=1024, NOUT=512, BSZ=64, STEPS=128.
// 256 blocks x 512 threads, 1 block/CU. Block (lyr, jt) owns 16 hidden cols of layer lyr.
// Round-24 (on r23 base, 898us): DROP BARRIER #3 via LDS completion counter.
//  r23's post-cell __syncthreads existed only so tid0 posts the flag after all waves
//  drained. Replace: each wave drains its OWN stores (vmcnt is wave-scoped), lane 0
//  does an LDS atomicAdd; the 8th wave posts the global flag + resets. Fast waves run
//  into the next phase's gemm while slow waves finish the cell. WAR on red removed by
//  DOUBLE-BUFFERING red by phase parity (= half, 2x36KB; LDS ~141KB). A wave can't get
//  >1 phase ahead (next phase's reduce barrier re-converges) -> 2-phase red reuse safe;
//  cS is thread-private per half. Barriers/phase 3 -> 2. Arithmetic unchanged.
// Unchanged from r23: batch-split half phases + cross-phase prefetch, depth-2 vmcnt
// ladder, 2-round reduce (RSTR=36), 512-thread cell, tiled write-once h slabs, plain
// cached A-loads, KL=512 LDS weights + 6 reg chunks, wave-granular flag wait,
// proj_kernel on slab 3.

#define H      1024
#define B      64
#define NL     4
#define BH     (B * H)
#define NOUTD  512
#define NSCAN  127
#define NWAVES 130
#define RSTR   36   // reduce tile stride (floats): 16B-aligned, 2-way banks
#define KL     512  // K columns resident in LDS per gate-row

typedef __attribute__((ext_vector_type(8))) short short8;
typedef __attribute__((ext_vector_type(4))) float f32x4;

__device__ __forceinline__ unsigned short f2bf(float x) {
  union { float f; unsigned int u; } v; v.f = x;
  unsigned int r = v.u + 0x7FFFu + ((v.u >> 16) & 1u);
  return (unsigned short)(r >> 16);
}
__device__ __forceinline__ short8 pack8(float4 a, float4 b) {
  short8 r;
  r[0] = (short)f2bf(a.x); r[1] = (short)f2bf(a.y);
  r[2] = (short)f2bf(a.z); r[3] = (short)f2bf(a.w);
  r[4] = (short)f2bf(b.x); r[5] = (short)f2bf(b.y);
  r[6] = (short)f2bf(b.z); r[7] = (short)f2bf(b.w);
  return r;
}
__device__ __forceinline__ float sigmoidf_(float x) {
  return 1.0f / (1.0f + __expf(-x));
}
__device__ __forceinline__ float tanhf_(float x) {
  float ax = fabsf(x);
  float t = __expf(-2.0f * ax);
  float r = 1.0f - 2.0f * t / (1.0f + t);
  return copysignf(r, x);
}

// PLAIN cached 16B load (L1+L2). Safe: h slabs are write-once, reads are flag-gated.
__device__ __forceinline__ void ldg16(short8* d, const unsigned short* p) {
  asm volatile("global_load_dwordx4 %0, %1, off" : "=v"(*d) : "v"(p));
}
#define VMWAIT2 do { asm volatile("s_waitcnt vmcnt(2)" ::: "memory"); \
                     __builtin_amdgcn_sched_barrier(0); } while (0)
#define VMWAIT0 do { asm volatile("s_waitcnt vmcnt(0)" ::: "memory"); \
                     __builtin_amdgcn_sched_barrier(0); } while (0)

__device__ __forceinline__ void st_h4(unsigned short* p, unsigned v) {
  __hip_atomic_store((unsigned*)p, v, __ATOMIC_RELAXED, __HIP_MEMORY_SCOPE_AGENT);
}
__device__ __forceinline__ void st_h2(unsigned short* p, unsigned short v) {
  __hip_atomic_store(p, v, __ATOMIC_RELAXED, __HIP_MEMORY_SCOPE_AGENT);
}

__global__ __launch_bounds__(512, 2)
__attribute__((amdgpu_waves_per_eu(2, 2)))
void lstm_persist(
    const float* __restrict__ hx, const float* __restrict__ cx,
    const float* __restrict__ Wm, const float* __restrict__ Um,
    unsigned short* __restrict__ hmon, unsigned* __restrict__ flags) {
  __shared__ __align__(16) unsigned short WuL[64 * KL];    // 64 KB swizzled gate weights
  __shared__ __align__(16) float red[2][4][64 * RSTR];     // 72 KB: double-buffered tiles
  __shared__ float cS[B * 16];                             // 4 KB cell state
  __shared__ unsigned ldsCnt[2];                           // per-parity completion count

  const int tid = threadIdx.x;
  const int q = tid >> 6;            // wave 0..7
  const int lane = tid & 63;
  const int l15 = lane & 15;
  const int lhi = lane >> 4;
  const int bid = blockIdx.x;
  const int lyr = bid >> 6;          // 0..3
  const int jt = bid & 63;           // 16-col group

  // monotonic slab: layer l holds positions l..l+127; 128KB each, TILED layout:
  // element (b, col) lives at (col>>5)*2048 + b*32 + (col&31)   [32 tiles of [64][32]]
#define HSL(l, p) (hmon + ((size_t)(l) * 128 + (size_t)((p) - (l))) * BH)
#define TOFF(b, col) (((size_t)((col) >> 5)) * 2048 + (size_t)(b) * 32 + ((col) & 31))
  // flag row w: [half][layer][jt] = 2*4*64 = 512 words (2KB per row)
#define FROW(w) (flags + (size_t)(w) * 512)

  // ---------------- init: h -> slab position lyr (tiled) + c ----------------
  {
    const int u = tid * 2;
    const int b = u >> 4, jj = u & 15;      // jj even
    const int C = jt * 16 + jj;             // global col, even
    const size_t gi = (size_t)lyr * BH + (size_t)b * H + C;
    const unsigned hv = (unsigned)f2bf(hx[gi]) | ((unsigned)f2bf(hx[gi + 1]) << 16);
    st_h4(HSL(lyr, lyr) + TOFF(b, C), hv);
    cS[b * 16 + jj] = cx[gi];
    cS[b * 16 + jj + 1] = cx[gi + 1];
  }
  if (tid < 2) ldsCnt[tid] = 0;

  // ---------------- weights: LDS part (K 0..511), swizzled ----------------
  {
    const int lr = tid >> 3;                 // local gate row 0..63
    const int kb0 = (tid & 7) * 64;          // K base (64 cols per thread)
    const int gr = (lr >> 4) * 1024 + jt * 16 + (lr & 15);
    const float* src = Um + ((size_t)lyr * 4096 + gr) * 1024 + kb0;
#pragma unroll
    for (int jc = 0; jc < 8; ++jc) {
      float4 f0 = *(const float4*)(src + jc * 8);
      float4 f1 = *(const float4*)(src + jc * 8 + 4);
      int byteoff = ((lr * KL + kb0 + jc * 8) * 2) ^ ((lr & 7) << 4);
      *(short8*)((char*)WuL + byteoff) = pack8(f0, f1);
    }
  }

  // ---------------- register weights (K >= 512): 6 chunks lyr>0, 2 chunks lyr0 ----------------
  short8 wreg[6][4];
  if (lyr == 0) {
#pragma unroll
    for (int c = 0; c < 2; ++c) {
      const int kk = KL + 64 * q + 32 * c + 8 * lhi;    // 512..1023
#pragma unroll
      for (int n = 0; n < 4; ++n) {
        const int gr = n * 1024 + jt * 16 + l15;
        const float* src = Um + (size_t)gr * 1024 + kk;
        wreg[c][n] = pack8(*(const float4*)src, *(const float4*)(src + 4));
      }
    }
  } else {
#pragma unroll
    for (int c = 0; c < 6; ++c) {
      const int kk = KL + 192 * q + 32 * c + 8 * lhi;   // 512..2047
#pragma unroll
      for (int n = 0; n < 4; ++n) {
        const int gr = n * 1024 + jt * 16 + l15;
        const float* src = (kk < 1024)
            ? (Um + ((size_t)lyr * 4096 + gr) * 1024 + kk)
            : (Wm + ((size_t)(lyr - 1) * 4096 + gr) * 1024 + (kk - 1024));
        wreg[c][n] = pack8(*(const float4*)src, *(const float4*)(src + 4));
      }
    }
  }

  // ---------------- post init flags (row 0, both halves) ----------------
  asm volatile("s_waitcnt vmcnt(0)" ::: "memory");
  __syncthreads();
  if (tid == 0) {
    __hip_atomic_store(FROW(0) + 0 * 256 + lyr * 64 + jt, 1u,
                       __ATOMIC_RELAXED, __HIP_MEMORY_SCOPE_AGENT);
    __hip_atomic_store(FROW(0) + 1 * 256 + lyr * 64 + jt, 1u,
                       __ATOMIC_RELAXED, __HIP_MEMORY_SCOPE_AGENT);
  }

  short8 A2[2][2];   // depth-2 pipeline buffers (shared across phases)

  // wave-granular dep wait (r17 mapping) on flag row base (already half-offset)
#define WAITDEPS(rowbase) { \
    const unsigned* _row = (rowbase); \
    const unsigned* _myf = nullptr; \
    if (lyr > 0) { \
      if (lane < 16) { \
        int _ll, _blk; \
        if (lane < 4) { _ll = lyr; _blk = 4 * q + lane; } \
        else { \
          const int _r = 32 + 12 * q + (lane - 4); \
          _ll = (_r >= 64) ? (lyr - 1) : lyr; \
          _blk = _r & 63; \
        } \
        _myf = _row + _ll * 64 + _blk; \
      } \
    } else { \
      if (lane < 8) { \
        const int _blk = (lane < 4) ? (4 * q + lane) : (32 + 4 * q + (lane - 4)); \
        _myf = _row + _blk; \
      } \
    } \
    if (_myf) \
      while (!__hip_atomic_load(_myf, __ATOMIC_RELAXED, __HIP_MEMORY_SCOPE_AGENT)) \
        __builtin_amdgcn_s_sleep(1); }

#define KSEL1(c)  ((c) < 2 ? (64 * q + 32 * (c)) : (KL + 192 * q + 32 * ((c) - 2)))
#define KSEL0(c)  ((c) < 2 ? (64 * q + 32 * (c)) : (KL + 64 * q + 32 * ((c) - 2)))
  // issue chunk with K-index k of phase (ww, hh) into buffer buf
#define ISSUE(buf, ww, hh, k) { \
    const unsigned short* _b = ((k) < 1024) \
      ? (HSL(lyr, (ww)) + (size_t)(hh) * 1024 + (size_t)l15 * 32 + lhi * 8 \
         + (size_t)((k) >> 5) * 2048) \
      : (HSL(lyr - 1, (ww)) + (size_t)(hh) * 1024 + (size_t)l15 * 32 + lhi * 8 \
         + (size_t)(((k) - 1024) >> 5) * 2048); \
    ldg16(&A2[buf][0], _b); \
    ldg16(&A2[buf][1], _b + 512); }
#define CONSUME(c) { \
    if ((c) < 2) { \
      const int kk = 64 * q + 32 * (c); \
      _Pragma("unroll") \
      for (int n = 0; n < 4; ++n) { \
        const int byteoff = (((n * 16 + l15) * KL + kk + 8 * lhi) * 2) ^ ((l15 & 7) << 4); \
        short8 bb = *(const short8*)((const char*)WuL + byteoff); \
        _Pragma("unroll") \
        for (int m = 0; m < 2; ++m) \
          acc[m][n] = __builtin_amdgcn_mfma_f32_16x16x32_bf16(A2[(c) & 1][m], bb, acc[m][n], 0, 0, 0); \
      } \
    } else { \
      _Pragma("unroll") \
      for (int n = 0; n < 4; ++n) \
        _Pragma("unroll") \
        for (int m = 0; m < 2; ++m) \
          acc[m][n] = __builtin_amdgcn_mfma_f32_16x16x32_bf16(A2[(c) & 1][m], wreg[(c) - 2][n], acc[m][n], 0, 0, 0); \
    } }

  bool pref = false;   // true: this phase's chunks 0,1 already waited-for and issued

  // ---------------- wavefront loop: two half-hop phases per hop ----------------
  for (int w = 0; w < NWAVES; ++w) {
    const int s = w - lyr;
    const bool active = (s >= 0 && s < NSCAN);

#pragma unroll
    for (int half = 0; half < 2; ++half) {
      const int nw = (half == 0) ? w : (w + 1);
      const int nh = (half == 0) ? 1 : 0;
      const bool nextActive = (half == 0) ? active
                              : ((w + 1 - lyr) >= 0 && (w + 1 - lyr) < NSCAN);
      if (active) {
        if (!pref) {
          WAITDEPS(FROW(w) + half * 256);
          if (lyr > 0) { ISSUE(0, w, half, KSEL1(0)); ISSUE(1, w, half, KSEL1(1)); }
          else         { ISSUE(0, w, half, KSEL0(0)); ISSUE(1, w, half, KSEL0(1)); }
        }

        f32x4 acc[2][4];
#pragma unroll
        for (int m = 0; m < 2; ++m)
#pragma unroll
          for (int n = 0; n < 4; ++n) acc[m][n] = (f32x4){0.f, 0.f, 0.f, 0.f};

        if (lyr > 0) {
#pragma unroll
          for (int c = 0; c < 8; ++c) {
            if (c == 7 && !nextActive) { VMWAIT0; } else { VMWAIT2; }
            CONSUME(c);
            if (c + 2 < 8) { ISSUE(c & 1, w, half, KSEL1(c + 2)); }
            else if (c == 6) {
              if (nextActive) { WAITDEPS(FROW(nw) + nh * 256); ISSUE(0, nw, nh, KSEL1(0)); }
            } else {  // c == 7
              if (nextActive) ISSUE(1, nw, nh, KSEL1(1));
            }
          }
        } else {
#pragma unroll
          for (int c = 0; c < 4; ++c) {
            if (c == 3 && !nextActive) { VMWAIT0; } else { VMWAIT2; }
            CONSUME(c);
            if (c + 2 < 4) { ISSUE(c & 1, w, half, KSEL0(c + 2)); }
            else if (c == 2) {
              if (nextActive) { WAITDEPS(FROW(nw) + nh * 256); ISSUE(0, nw, nh, KSEL0(0)); }
            } else {  // c == 3
              if (nextActive) ISSUE(1, nw, nh, KSEL0(1));
            }
          }
        }

        // 2-round reduce into THIS PARITY's red buffer: waves 0-3 write, sync,
        // waves 4-7 add, sync.
        {
          float* tile = red[half][q & 3];
          if (q < 4) {
#pragma unroll
            for (int m = 0; m < 2; ++m)
#pragma unroll
              for (int n = 0; n < 4; ++n)
                *(f32x4*)&tile[(n * 16 + l15) * RSTR + m * 16 + lhi * 4] = acc[m][n];
          }
          __syncthreads();
          if (q >= 4) {
#pragma unroll
            for (int m = 0; m < 2; ++m)
#pragma unroll
              for (int n = 0; n < 4; ++n) {
                float* p = &tile[(n * 16 + l15) * RSTR + m * 16 + lhi * 4];
                f32x4 v = *(f32x4*)p; v += acc[m][n]; *(f32x4*)p = v;
              }
          }
          __syncthreads();
        }

        // fused LSTM cell for this half: ALL 512 threads, 1 element each.
        // Then per-wave drain + LDS completion counter; 8th wave posts the flag.
        // NO block barrier: fast waves proceed into the next phase's gemm.
        {
          const int bl = tid >> 4, jj = tid & 15;  // bl local 0..31
          const int b = bl + half * 32;
          const int C = jt * 16 + jj;              // global col
          float ig = 0.f, fg = 0.f, gg = 0.f, og = 0.f;
#pragma unroll
          for (int t = 0; t < 4; ++t) {
            ig += red[half][t][(0 * 16 + jj) * RSTR + bl];
            fg += red[half][t][(1 * 16 + jj) * RSTR + bl];
            gg += red[half][t][(2 * 16 + jj) * RSTR + bl];
            og += red[half][t][(3 * 16 + jj) * RSTR + bl];
          }
          const float i_ = sigmoidf_(ig);
          const float f_ = sigmoidf_(fg);
          const float g_ = tanhf_(gg);
          const float o_ = sigmoidf_(og);
          const float cv = f_ * cS[b * 16 + jj] + i_ * g_;
          cS[b * 16 + jj] = cv;
          st_h2(HSL(lyr, w + 1) + TOFF(b, C), f2bf(o_ * tanhf_(cv)));
          asm volatile("s_waitcnt vmcnt(0)" ::: "memory");   // wave-scope drain (+prefetch)
          if (lane == 0) {
            const unsigned c = atomicAdd(&ldsCnt[half], 1u);
            if (c == 7u) {
              ldsCnt[half] = 0u;
              __hip_atomic_store(FROW(w + 1) + half * 256 + lyr * 64 + jt, 1u,
                                 __ATOMIC_RELAXED, __HIP_MEMORY_SCOPE_AGENT);
            }
          }
        }
        pref = nextActive;
      } else {
        // idle hop: keep this half's flag row complete
        if (tid == 0)
          __hip_atomic_store(FROW(w + 1) + half * 256 + lyr * 64 + jt, 1u,
                             __ATOMIC_RELAXED, __HIP_MEMORY_SCOPE_AGENT);
        pref = false;
      }
    }
  }
#undef HSL
#undef TOFF
#undef FROW
#undef WAITDEPS
#undef KSEL1
#undef KSEL0
#undef ISSUE
#undef CONSUME
}

// ---------------- batched output projection: out[t] = h3[t] @ L^T ----------------
// h3 history = layer-3 monotonic slab (TILED layout), position t at slab index t.
// M = 8192 (= 128 positions x 64 rows), N = 512, K = 1024. mt = position index.
__global__ __launch_bounds__(256) void proj_kernel(
    const unsigned short* __restrict__ hist, const float* __restrict__ Lm,
    float* __restrict__ out) {
  __shared__ __align__(16) unsigned short As[64 * 136];
  const int tid = threadIdx.x;
  const int q = tid >> 6;
  const int lane = tid & 63;
  const int l15 = lane & 15;
  const int lhi = lane >> 4;
  const int mt = blockIdx.x >> 3;   // position (time) index 0..127
  const int nt = blockIdx.x & 7;

  f32x4 acc[4];
#pragma unroll
  for (int m = 0; m < 4; ++m) acc[m] = (f32x4){0.f, 0.f, 0.f, 0.f};

  for (int kb = 0; kb < 8; ++kb) {
    __syncthreads();
#pragma unroll
    for (int i = 0; i < 4; ++i) {
      int g = tid + 256 * i;
      int row = g >> 4, cu = g & 15;
      const int C = kb * 128 + cu * 8;   // global k-col of the 8-elem chunk
      *(short8*)(&As[row * 136 + cu * 8]) =
          *(const short8*)(&hist[(size_t)mt * 65536 + (size_t)(C >> 5) * 2048
                                 + (size_t)row * 32 + (C & 31)]);
    }
    __syncthreads();
#pragma unroll
    for (int kk = 0; kk < 4; ++kk) {
      const int ko = kk * 32 + 8 * lhi;
      const float* src = Lm + ((size_t)nt * 64 + q * 16 + l15) * H + kb * 128 + ko;
      short8 bb = pack8(*(const float4*)src, *(const float4*)(src + 4));
#pragma unroll
      for (int m = 0; m < 4; ++m) {
        short8 a = *(const short8*)(&As[(m * 16 + l15) * 136 + ko]);
        acc[m] = __builtin_amdgcn_mfma_f32_16x16x32_bf16(a, bb, acc[m], 0, 0, 0);
      }
    }
  }
  const int col = nt * 64 + q * 16 + l15;
#pragma unroll
  for (int m = 0; m < 4; ++m)
#pragma unroll
    for (int j = 0; j < 4; ++j) {
      const int row = mt * 64 + m * 16 + lhi * 4 + j;
      out[(size_t)row * NOUTD + col] = acc[m][j];
    }
}

extern "C" void kernel_launch(void* const* d_in, const int* in_sizes, int n_in,
                              void* d_out, int out_size, void* d_ws, size_t ws_size,
                              hipStream_t stream) {
  const float* hx = (const float*)d_in[0];
  const float* cx = (const float*)d_in[1];
  const float* Wm = (const float*)d_in[2];
  const float* Um = (const float*)d_in[3];
  const float* Lm = (const float*)d_in[4];
  float* out = (float*)d_out;

  char* ws = (char*)d_ws;
  unsigned* flags = (unsigned*)ws;                              // 512 KB flag rows
  unsigned short* hmon = (unsigned short*)(ws + (1 << 19));     // 64 MiB monotonic h slabs

  hipMemsetAsync(flags, 0, 1 << 19, stream);

  void* args[] = {(void*)&hx, (void*)&cx, (void*)&Wm, (void*)&Um,
                  (void*)&hmon, (void*)&flags};
  hipLaunchCooperativeKernel((const void*)lstm_persist, dim3(256), dim3(512),
                             args, 0, stream);
  // layer-3 slab base: position t+3 lives at slab index t => history row-block t
  const unsigned short* hist = hmon + (size_t)3 * 128 * BH;
  proj_kernel<<<dim3(1024), dim3(256), 0, stream>>>(hist, Lm, out);
}

// Round 25
// 897.404 us; speedup vs baseline: 1.0775x; 1.0775x over previous
//
#include <hip/hip_runtime.h>

// Persistent cooperative LSTM decoder. NLAYERS=4, NHID=1024, NOUT=512, BSZ=64, STEPS=128.
// 256 blocks x 512 threads, 1 block/CU. Block (lyr, jt) owns 16 hidden cols of layer lyr.
// FINAL (= round-23, 898us): r24's LDS-counter flag post regressed -> reverted.
// Structure: batch-split half-hop pipeline + cross-phase prefetch + depth-2 vmcnt
// ladder + 2-round reduce + 512-thread cell; tiled write-once h slabs with plain
// cached A-loads; KL=512 LDS weights + 6 reg chunks; wave-granular flag wait;
// separate proj_kernel on the layer-3 slab.

#define H      1024
#define B      64
#define NL     4
#define BH     (B * H)
#define NOUTD  512
#define NSCAN  127
#define NWAVES 130
#define RSTR   36   // reduce tile stride (floats): 16B-aligned, 2-way banks
#define KL     512  // K columns resident in LDS per gate-row

typedef __attribute__((ext_vector_type(8))) short short8;
typedef __attribute__((ext_vector_type(4))) float f32x4;

__device__ __forceinline__ unsigned short f2bf(float x) {
  union { float f; unsigned int u; } v; v.f = x;
  unsigned int r = v.u + 0x7FFFu + ((v.u >> 16) & 1u);
  return (unsigned short)(r >> 16);
}
__device__ __forceinline__ short8 pack8(float4 a, float4 b) {
  short8 r;
  r[0] = (short)f2bf(a.x); r[1] = (short)f2bf(a.y);
  r[2] = (short)f2bf(a.z); r[3] = (short)f2bf(a.w);
  r[4] = (short)f2bf(b.x); r[5] = (short)f2bf(b.y);
  r[6] = (short)f2bf(b.z); r[7] = (short)f2bf(b.w);
  return r;
}
__device__ __forceinline__ float sigmoidf_(float x) {
  return 1.0f / (1.0f + __expf(-x));
}
__device__ __forceinline__ float tanhf_(float x) {
  float ax = fabsf(x);
  float t = __expf(-2.0f * ax);
  float r = 1.0f - 2.0f * t / (1.0f + t);
  return copysignf(r, x);
}

// PLAIN cached 16B load (L1+L2). Safe: h slabs are write-once, reads are flag-gated.
__device__ __forceinline__ void ldg16(short8* d, const unsigned short* p) {
  asm volatile("global_load_dwordx4 %0, %1, off" : "=v"(*d) : "v"(p));
}
#define VMWAIT2 do { asm volatile("s_waitcnt vmcnt(2)" ::: "memory"); \
                     __builtin_amdgcn_sched_barrier(0); } while (0)
#define VMWAIT0 do { asm volatile("s_waitcnt vmcnt(0)" ::: "memory"); \
                     __builtin_amdgcn_sched_barrier(0); } while (0)

__device__ __forceinline__ void st_h4(unsigned short* p, unsigned v) {
  __hip_atomic_store((unsigned*)p, v, __ATOMIC_RELAXED, __HIP_MEMORY_SCOPE_AGENT);
}
__device__ __forceinline__ void st_h2(unsigned short* p, unsigned short v) {
  __hip_atomic_store(p, v, __ATOMIC_RELAXED, __HIP_MEMORY_SCOPE_AGENT);
}

__global__ __launch_bounds__(512, 2)
__attribute__((amdgpu_waves_per_eu(2, 2)))
void lstm_persist(
    const float* __restrict__ hx, const float* __restrict__ cx,
    const float* __restrict__ Wm, const float* __restrict__ Um,
    unsigned short* __restrict__ hmon, unsigned* __restrict__ flags) {
  __shared__ __align__(16) unsigned short WuL[64 * KL];    // 64 KB swizzled gate weights
  __shared__ __align__(16) float red[4][64 * RSTR];        // 36 KB: 4 reduce tiles
  __shared__ float cS[B * 16];                             // 4 KB cell state

  const int tid = threadIdx.x;
  const int q = tid >> 6;            // wave 0..7
  const int lane = tid & 63;
  const int l15 = lane & 15;
  const int lhi = lane >> 4;
  const int bid = blockIdx.x;
  const int lyr = bid >> 6;          // 0..3
  const int jt = bid & 63;           // 16-col group

  // monotonic slab: layer l holds positions l..l+127; 128KB each, TILED layout:
  // element (b, col) lives at (col>>5)*2048 + b*32 + (col&31)   [32 tiles of [64][32]]
#define HSL(l, p) (hmon + ((size_t)(l) * 128 + (size_t)((p) - (l))) * BH)
#define TOFF(b, col) (((size_t)((col) >> 5)) * 2048 + (size_t)(b) * 32 + ((col) & 31))
  // flag row w: [half][layer][jt] = 2*4*64 = 512 words (2KB per row)
#define FROW(w) (flags + (size_t)(w) * 512)

  // ---------------- init: h -> slab position lyr (tiled) + c ----------------
  {
    const int u = tid * 2;
    const int b = u >> 4, jj = u & 15;      // jj even
    const int C = jt * 16 + jj;             // global col, even
    const size_t gi = (size_t)lyr * BH + (size_t)b * H + C;
    const unsigned hv = (unsigned)f2bf(hx[gi]) | ((unsigned)f2bf(hx[gi + 1]) << 16);
    st_h4(HSL(lyr, lyr) + TOFF(b, C), hv);
    cS[b * 16 + jj] = cx[gi];
    cS[b * 16 + jj + 1] = cx[gi + 1];
  }

  // ---------------- weights: LDS part (K 0..511), swizzled ----------------
  {
    const int lr = tid >> 3;                 // local gate row 0..63
    const int kb0 = (tid & 7) * 64;          // K base (64 cols per thread)
    const int gr = (lr >> 4) * 1024 + jt * 16 + (lr & 15);
    const float* src = Um + ((size_t)lyr * 4096 + gr) * 1024 + kb0;
#pragma unroll
    for (int jc = 0; jc < 8; ++jc) {
      float4 f0 = *(const float4*)(src + jc * 8);
      float4 f1 = *(const float4*)(src + jc * 8 + 4);
      int byteoff = ((lr * KL + kb0 + jc * 8) * 2) ^ ((lr & 7) << 4);
      *(short8*)((char*)WuL + byteoff) = pack8(f0, f1);
    }
  }

  // ---------------- register weights (K >= 512): 6 chunks lyr>0, 2 chunks lyr0 ----------------
  short8 wreg[6][4];
  if (lyr == 0) {
#pragma unroll
    for (int c = 0; c < 2; ++c) {
      const int kk = KL + 64 * q + 32 * c + 8 * lhi;    // 512..1023
#pragma unroll
      for (int n = 0; n < 4; ++n) {
        const int gr = n * 1024 + jt * 16 + l15;
        const float* src = Um + (size_t)gr * 1024 + kk;
        wreg[c][n] = pack8(*(const float4*)src, *(const float4*)(src + 4));
      }
    }
  } else {
#pragma unroll
    for (int c = 0; c < 6; ++c) {
      const int kk = KL + 192 * q + 32 * c + 8 * lhi;   // 512..2047
#pragma unroll
      for (int n = 0; n < 4; ++n) {
        const int gr = n * 1024 + jt * 16 + l15;
        const float* src = (kk < 1024)
            ? (Um + ((size_t)lyr * 4096 + gr) * 1024 + kk)
            : (Wm + ((size_t)(lyr - 1) * 4096 + gr) * 1024 + (kk - 1024));
        wreg[c][n] = pack8(*(const float4*)src, *(const float4*)(src + 4));
      }
    }
  }

  // ---------------- post init flags (row 0, both halves) ----------------
  asm volatile("s_waitcnt vmcnt(0)" ::: "memory");
  __syncthreads();
  if (tid == 0) {
    __hip_atomic_store(FROW(0) + 0 * 256 + lyr * 64 + jt, 1u,
                       __ATOMIC_RELAXED, __HIP_MEMORY_SCOPE_AGENT);
    __hip_atomic_store(FROW(0) + 1 * 256 + lyr * 64 + jt, 1u,
                       __ATOMIC_RELAXED, __HIP_MEMORY_SCOPE_AGENT);
  }

  short8 A2[2][2];   // depth-2 pipeline buffers (shared across phases)

  // wave-granular dep wait (r17 mapping) on flag row base (already half-offset)
#define WAITDEPS(rowbase) { \
    const unsigned* _row = (rowbase); \
    const unsigned* _myf = nullptr; \
    if (lyr > 0) { \
      if (lane < 16) { \
        int _ll, _blk; \
        if (lane < 4) { _ll = lyr; _blk = 4 * q + lane; } \
        else { \
          const int _r = 32 + 12 * q + (lane - 4); \
          _ll = (_r >= 64) ? (lyr - 1) : lyr; \
          _blk = _r & 63; \
        } \
        _myf = _row + _ll * 64 + _blk; \
      } \
    } else { \
      if (lane < 8) { \
        const int _blk = (lane < 4) ? (4 * q + lane) : (32 + 4 * q + (lane - 4)); \
        _myf = _row + _blk; \
      } \
    } \
    if (_myf) \
      while (!__hip_atomic_load(_myf, __ATOMIC_RELAXED, __HIP_MEMORY_SCOPE_AGENT)) \
        __builtin_amdgcn_s_sleep(1); }

#define KSEL1(c)  ((c) < 2 ? (64 * q + 32 * (c)) : (KL + 192 * q + 32 * ((c) - 2)))
#define KSEL0(c)  ((c) < 2 ? (64 * q + 32 * (c)) : (KL + 64 * q + 32 * ((c) - 2)))
  // issue chunk with K-index k of phase (ww, hh) into buffer buf
#define ISSUE(buf, ww, hh, k) { \
    const unsigned short* _b = ((k) < 1024) \
      ? (HSL(lyr, (ww)) + (size_t)(hh) * 1024 + (size_t)l15 * 32 + lhi * 8 \
         + (size_t)((k) >> 5) * 2048) \
      : (HSL(lyr - 1, (ww)) + (size_t)(hh) * 1024 + (size_t)l15 * 32 + lhi * 8 \
         + (size_t)(((k) - 1024) >> 5) * 2048); \
    ldg16(&A2[buf][0], _b); \
    ldg16(&A2[buf][1], _b + 512); }
#define CONSUME(c) { \
    if ((c) < 2) { \
      const int kk = 64 * q + 32 * (c); \
      _Pragma("unroll") \
      for (int n = 0; n < 4; ++n) { \
        const int byteoff = (((n * 16 + l15) * KL + kk + 8 * lhi) * 2) ^ ((l15 & 7) << 4); \
        short8 bb = *(const short8*)((const char*)WuL + byteoff); \
        _Pragma("unroll") \
        for (int m = 0; m < 2; ++m) \
          acc[m][n] = __builtin_amdgcn_mfma_f32_16x16x32_bf16(A2[(c) & 1][m], bb, acc[m][n], 0, 0, 0); \
      } \
    } else { \
      _Pragma("unroll") \
      for (int n = 0; n < 4; ++n) \
        _Pragma("unroll") \
        for (int m = 0; m < 2; ++m) \
          acc[m][n] = __builtin_amdgcn_mfma_f32_16x16x32_bf16(A2[(c) & 1][m], wreg[(c) - 2][n], acc[m][n], 0, 0, 0); \
    } }

  bool pref = false;   // true: this phase's chunks 0,1 already waited-for and issued

  // ---------------- wavefront loop: two half-hop phases per hop ----------------
  for (int w = 0; w < NWAVES; ++w) {
    const int s = w - lyr;
    const bool active = (s >= 0 && s < NSCAN);

#pragma unroll
    for (int half = 0; half < 2; ++half) {
      const int nw = (half == 0) ? w : (w + 1);
      const int nh = (half == 0) ? 1 : 0;
      const bool nextActive = (half == 0) ? active
                              : ((w + 1 - lyr) >= 0 && (w + 1 - lyr) < NSCAN);
      if (active) {
        if (!pref) {
          WAITDEPS(FROW(w) + half * 256);
          if (lyr > 0) { ISSUE(0, w, half, KSEL1(0)); ISSUE(1, w, half, KSEL1(1)); }
          else         { ISSUE(0, w, half, KSEL0(0)); ISSUE(1, w, half, KSEL0(1)); }
        }

        f32x4 acc[2][4];
#pragma unroll
        for (int m = 0; m < 2; ++m)
#pragma unroll
          for (int n = 0; n < 4; ++n) acc[m][n] = (f32x4){0.f, 0.f, 0.f, 0.f};

        if (lyr > 0) {
#pragma unroll
          for (int c = 0; c < 8; ++c) {
            if (c == 7 && !nextActive) { VMWAIT0; } else { VMWAIT2; }
            CONSUME(c);
            if (c + 2 < 8) { ISSUE(c & 1, w, half, KSEL1(c + 2)); }
            else if (c == 6) {
              if (nextActive) { WAITDEPS(FROW(nw) + nh * 256); ISSUE(0, nw, nh, KSEL1(0)); }
            } else {  // c == 7
              if (nextActive) ISSUE(1, nw, nh, KSEL1(1));
            }
          }
        } else {
#pragma unroll
          for (int c = 0; c < 4; ++c) {
            if (c == 3 && !nextActive) { VMWAIT0; } else { VMWAIT2; }
            CONSUME(c);
            if (c + 2 < 4) { ISSUE(c & 1, w, half, KSEL0(c + 2)); }
            else if (c == 2) {
              if (nextActive) { WAITDEPS(FROW(nw) + nh * 256); ISSUE(0, nw, nh, KSEL0(0)); }
            } else {  // c == 3
              if (nextActive) ISSUE(1, nw, nh, KSEL0(1));
            }
          }
        }

        // 2-round reduce: waves 0-3 write tiles 0-3, sync, waves 4-7 add, sync.
        {
          float* tile = red[q & 3];
          if (q < 4) {
#pragma unroll
            for (int m = 0; m < 2; ++m)
#pragma unroll
              for (int n = 0; n < 4; ++n)
                *(f32x4*)&tile[(n * 16 + l15) * RSTR + m * 16 + lhi * 4] = acc[m][n];
          }
          __syncthreads();
          if (q >= 4) {
#pragma unroll
            for (int m = 0; m < 2; ++m)
#pragma unroll
              for (int n = 0; n < 4; ++n) {
                float* p = &tile[(n * 16 + l15) * RSTR + m * 16 + lhi * 4];
                f32x4 v = *(f32x4*)p; v += acc[m][n]; *(f32x4*)p = v;
              }
          }
          __syncthreads();
        }

        // fused LSTM cell for this half: ALL 512 threads, 1 element each
        {
          const int bl = tid >> 4, jj = tid & 15;  // bl local 0..31
          const int b = bl + half * 32;
          const int C = jt * 16 + jj;              // global col
          float ig = 0.f, fg = 0.f, gg = 0.f, og = 0.f;
#pragma unroll
          for (int t = 0; t < 4; ++t) {
            ig += red[t][(0 * 16 + jj) * RSTR + bl];
            fg += red[t][(1 * 16 + jj) * RSTR + bl];
            gg += red[t][(2 * 16 + jj) * RSTR + bl];
            og += red[t][(3 * 16 + jj) * RSTR + bl];
          }
          const float i_ = sigmoidf_(ig);
          const float f_ = sigmoidf_(fg);
          const float g_ = tanhf_(gg);
          const float o_ = sigmoidf_(og);
          const float cv = f_ * cS[b * 16 + jj] + i_ * g_;
          cS[b * 16 + jj] = cv;
          st_h2(HSL(lyr, w + 1) + TOFF(b, C), f2bf(o_ * tanhf_(cv)));
          asm volatile("s_waitcnt vmcnt(0)" ::: "memory");   // drain h-stores (+prefetch)
        }
        __syncthreads();
        if (tid == 0)
          __hip_atomic_store(FROW(w + 1) + half * 256 + lyr * 64 + jt, 1u,
                             __ATOMIC_RELAXED, __HIP_MEMORY_SCOPE_AGENT);
        pref = nextActive;
      } else {
        // idle hop: keep this half's flag row complete
        if (tid == 0)
          __hip_atomic_store(FROW(w + 1) + half * 256 + lyr * 64 + jt, 1u,
                             __ATOMIC_RELAXED, __HIP_MEMORY_SCOPE_AGENT);
        pref = false;
      }
    }
  }
#undef HSL
#undef TOFF
#undef FROW
#undef WAITDEPS
#undef KSEL1
#undef KSEL0
#undef ISSUE
#undef CONSUME
}

// ---------------- batched output projection: out[t] = h3[t] @ L^T ----------------
// h3 history = layer-3 monotonic slab (TILED layout), position t at slab index t.
// M = 8192 (= 128 positions x 64 rows), N = 512, K = 1024. mt = position index.
__global__ __launch_bounds__(256) void proj_kernel(
    const unsigned short* __restrict__ hist, const float* __restrict__ Lm,
    float* __restrict__ out) {
  __shared__ __align__(16) unsigned short As[64 * 136];
  const int tid = threadIdx.x;
  const int q = tid >> 6;
  const int lane = tid & 63;
  const int l15 = lane & 15;
  const int lhi = lane >> 4;
  const int mt = blockIdx.x >> 3;   // position (time) index 0..127
  const int nt = blockIdx.x & 7;

  f32x4 acc[4];
#pragma unroll
  for (int m = 0; m < 4; ++m) acc[m] = (f32x4){0.f, 0.f, 0.f, 0.f};

  for (int kb = 0; kb < 8; ++kb) {
    __syncthreads();
#pragma unroll
    for (int i = 0; i < 4; ++i) {
      int g = tid + 256 * i;
      int row = g >> 4, cu = g & 15;
      const int C = kb * 128 + cu * 8;   // global k-col of the 8-elem chunk
      *(short8*)(&As[row * 136 + cu * 8]) =
          *(const short8*)(&hist[(size_t)mt * 65536 + (size_t)(C >> 5) * 2048
                                 + (size_t)row * 32 + (C & 31)]);
    }
    __syncthreads();
#pragma unroll
    for (int kk = 0; kk < 4; ++kk) {
      const int ko = kk * 32 + 8 * lhi;
      const float* src = Lm + ((size_t)nt * 64 + q * 16 + l15) * H + kb * 128 + ko;
      short8 bb = pack8(*(const float4*)src, *(const float4*)(src + 4));
#pragma unroll
      for (int m = 0; m < 4; ++m) {
        short8 a = *(const short8*)(&As[(m * 16 + l15) * 136 + ko]);
        acc[m] = __builtin_amdgcn_mfma_f32_16x16x32_bf16(a, bb, acc[m], 0, 0, 0);
      }
    }
  }
  const int col = nt * 64 + q * 16 + l15;
#pragma unroll
  for (int m = 0; m < 4; ++m)
#pragma unroll
    for (int j = 0; j < 4; ++j) {
      const int row = mt * 64 + m * 16 + lhi * 4 + j;
      out[(size_t)row * NOUTD + col] = acc[m][j];
    }
}

extern "C" void kernel_launch(void* const* d_in, const int* in_sizes, int n_in,
                              void* d_out, int out_size, void* d_ws, size_t ws_size,
                              hipStream_t stream) {
  const float* hx = (const float*)d_in[0];
  const float* cx = (const float*)d_in[1];
  const float* Wm = (const float*)d_in[2];
  const float* Um = (const float*)d_in[3];
  const float* Lm = (const float*)d_in[4];
  float* out = (float*)d_out;

  char* ws = (char*)d_ws;
  unsigned* flags = (unsigned*)ws;                              // 512 KB flag rows
  unsigned short* hmon = (unsigned short*)(ws + (1 << 19));     // 64 MiB monotonic h slabs

  hipMemsetAsync(flags, 0, 1 << 19, stream);

  void* args[] = {(void*)&hx, (void*)&cx, (void*)&Wm, (void*)&Um,
                  (void*)&hmon, (void*)&flags};
  hipLaunchCooperativeKernel((const void*)lstm_persist, dim3(256), dim3(512),
                             args, 0, stream);
  // layer-3 slab base: position t+3 lives at slab index t => history row-block t
  const unsigned short* hist = hmon + (size_t)3 * 128 * BH;
  proj_kernel<<<dim3(1024), dim3(256), 0, stream>>>(hist, Lm, out);
}